// Round 13
// baseline (116.862 us; speedup 1.0000x reference)
//
#include <hip/hip_runtime.h>
#include <math.h>

typedef _Float16 f16;
typedef f16   f16x4    __attribute__((ext_vector_type(4)));
typedef f16   f16x8    __attribute__((ext_vector_type(8)));
typedef float floatx2  __attribute__((ext_vector_type(2)));
typedef float floatx4  __attribute__((ext_vector_type(4)));
typedef float floatx16 __attribute__((ext_vector_type(16)));

#define LOG2E   1.44269504088896340736f
#define INV_2PI 0.15915494309189533577f

// Problem constants
#define B_SZ  2048
#define DIN   64
#define DOUT  64
#define N_HID 32

#define NIG   2                 // i-groups (4096 blocks, 32 iters each)
#define IGW   (DIN / NIG)       // 32 i per block

// Images (built by prep_kernel), K=8-packed for mfma_32x32x8:
//  w1img  f16 [i][o][lane(64)][j(4)]: A1-frag, m=h=lane&31, k=(lane>>5)*4+j.
//         lane<32 -> k=0..3 -> W1[...,{x,s1,s2,s4}]; lane>=32 -> k=4..7 ->
//         {W1[4],W1[5],W1[6],B1}. Scaled by -log2e. MFMA1 -> a'' = -log2e*a.
//  w12img f16: same layout, additionally scaled by W2[i,o,h] per row.
//         MFMA2 -> u'' = -log2e * a * W2 directly.
//  fimg   f16 [i][btp(64)][lane(64)][j(4)]: B-frag; lane<32 {x,s1,s2,s4},
//         lane>=32 {c1,c2,c4,1}.
//  b2sum  f32 [64]: column sums of B2.
#define W1IMG_ELEMS ((size_t)DIN * DOUT * 64 * 4)   // 1,048,576 f16 = 2 MB
#define FIMG_ELEMS  ((size_t)DIN * 64 * 64 * 4)     // 1,048,576 f16 = 2 MB

// ---- packed-f32 (VOP3P) helpers ----
__device__ __forceinline__ floatx2 pk_add(floatx2 a, floatx2 b) {
    floatx2 d; asm("v_pk_add_f32 %0, %1, %2" : "=v"(d) : "v"(a), "v"(b)); return d;
}
__device__ __forceinline__ floatx2 pk_mul(floatx2 a, floatx2 b) {
    floatx2 d; asm("v_pk_mul_f32 %0, %1, %2" : "=v"(d) : "v"(a), "v"(b)); return d;
}
__device__ __forceinline__ floatx2 pk_fma(floatx2 a, floatx2 b, floatx2 c) {
    floatx2 d; asm("v_pk_fma_f32 %0, %1, %2, %3" : "=v"(d) : "v"(a), "v"(b), "v"(c)); return d;
}

// ---------------------------------------------------------------------------
// prep: bid [0,512) w1img, [512,1024) w12img, [1024,1536) fimg,
// [1536,1664) zero out[], 1664 b2sum. sin/cos via HW v_sin/v_cos.
// ---------------------------------------------------------------------------
__global__ __launch_bounds__(256) void prep_kernel(
        const float* __restrict__ W1, const float* __restrict__ B1,
        const float* __restrict__ W2, const float* __restrict__ B2,
        const float* __restrict__ x,
        f16* __restrict__ w1img, f16* __restrict__ w12img,
        f16* __restrict__ fimg, float* __restrict__ b2sum,
        float* __restrict__ out) {
    const int bid = blockIdx.x, tid = threadIdx.x;
    if (bid < 1024) {
        const bool second = bid >= 512;
        int u = (second ? bid - 512 : bid) * 256 + tid;  // [i][o][lane2]
        int lane2 = u & 31, o = (u >> 5) & 63, i = u >> 11;
        int l0 = lane2 * 2;
        f16x8 v;
        if (lane2 < 16) {                    // rows l0,l0+1; k=0..3 -> w[0..3]
#pragma unroll
            for (int t = 0; t < 2; ++t) {
                int m = l0 + t;
                float sc = -LOG2E;
                if (second) sc *= W2[(size_t)(i * 64 + o) * 32 + m];
                const float* w = W1 + (size_t)((i * 64 + o) * 32 + m) * 7;
#pragma unroll
                for (int j = 0; j < 4; ++j) v[t * 4 + j] = (f16)(w[j] * sc);
            }
        } else {                             // rows l0-32..; k=4..7 -> w[4..6],B1
#pragma unroll
            for (int t = 0; t < 2; ++t) {
                int m = l0 - 32 + t;
                float sc = -LOG2E;
                if (second) sc *= W2[(size_t)(i * 64 + o) * 32 + m];
                const float* w = W1 + (size_t)((i * 64 + o) * 32 + m) * 7;
                v[t * 4 + 0] = (f16)(w[4] * sc);
                v[t * 4 + 1] = (f16)(w[5] * sc);
                v[t * 4 + 2] = (f16)(w[6] * sc);
                v[t * 4 + 3] = (f16)(B1[(i * 64 + o) * 32 + m] * sc);
            }
        }
        *(f16x8*)((second ? w12img : w1img) + (size_t)u * 8) = v;
    } else if (bid < 1536) {
        int u = (bid - 1024) * 256 + tid;    // [i][btp][lane2]
        int lane2 = u & 31, btp = (u >> 5) & 63, i = u >> 11;
        int l0 = lane2 * 2;
        f16x8 v;
#pragma unroll
        for (int t = 0; t < 2; ++t) {
            int b = btp * 32 + ((l0 + t) & 31);
            float xv = x[b * 64 + i];
            float s1 = __builtin_amdgcn_sinf(xv * INV_2PI);
            float c1 = __builtin_amdgcn_cosf(xv * INV_2PI);
            float s2 = 2.0f * s1 * c1, c2 = 1.0f - 2.0f * s1 * s1;
            float s4 = 2.0f * s2 * c2, c4 = 1.0f - 2.0f * s2 * s2;
            if (lane2 < 16) { v[t*4+0] = (f16)xv; v[t*4+1] = (f16)s1;
                              v[t*4+2] = (f16)s2; v[t*4+3] = (f16)s4; }
            else            { v[t*4+0] = (f16)c1; v[t*4+1] = (f16)c2;
                              v[t*4+2] = (f16)c4; v[t*4+3] = (f16)1.0f; }
        }
        *(f16x8*)(fimg + (size_t)u * 8) = v;
    } else if (bid < 1664) {
        int t = (bid - 1536) * 256 + tid;    // zero out[] (atomics accumulate)
        floatx4 z = {};
        *(floatx4*)(out + (size_t)t * 4) = z;
    } else if (tid < 64) {
        float s = 0.0f;
        for (int i = 0; i < 64; ++i) s += B2[i * 64 + tid];
        b2sum[tid] = s;
    }
}

// silu-sum over 16 activations (both r-halves) with a 16-WAY batched
// reciprocal: two 8-way trees (pk lanes = 2 r-groups each) merged scalarly
// -> ONE rcp per 16 activations. 26 pk + 10 scalar + 17 trans.
//   d_i = 1 + 2^(a''_i) (a'' from MFMA1), u''_i = W2*a'' (from MFMA2);
//   phi += sum u''_i/d_i. Overflow: d16 <= e^(sum positive a'' over 16);
//   a''~N(0,0.65) here -> group sums <~15 vs f32 limit 88.
__device__ __forceinline__ void silu16(
        const floatx16& C1, const floatx16& C2, floatx2 one2, float& phi) {
    // lo half r=0,1
    floatx2 E0 = {__builtin_amdgcn_exp2f(C1[0]),  __builtin_amdgcn_exp2f(C1[1])};
    floatx2 E1 = {__builtin_amdgcn_exp2f(C1[4]),  __builtin_amdgcn_exp2f(C1[5])};
    floatx2 E2 = {__builtin_amdgcn_exp2f(C1[8]),  __builtin_amdgcn_exp2f(C1[9])};
    floatx2 E3 = {__builtin_amdgcn_exp2f(C1[12]), __builtin_amdgcn_exp2f(C1[13])};
    // hi half r=2,3
    floatx2 F0 = {__builtin_amdgcn_exp2f(C1[2]),  __builtin_amdgcn_exp2f(C1[3])};
    floatx2 F1 = {__builtin_amdgcn_exp2f(C1[6]),  __builtin_amdgcn_exp2f(C1[7])};
    floatx2 F2 = {__builtin_amdgcn_exp2f(C1[10]), __builtin_amdgcn_exp2f(C1[11])};
    floatx2 F3 = {__builtin_amdgcn_exp2f(C1[14]), __builtin_amdgcn_exp2f(C1[15])};
    floatx2 D0 = pk_add(E0, one2), D1 = pk_add(E1, one2);
    floatx2 D2 = pk_add(E2, one2), D3 = pk_add(E3, one2);
    floatx2 G0 = pk_add(F0, one2), G1 = pk_add(F1, one2);
    floatx2 G2 = pk_add(F2, one2), G3 = pk_add(F3, one2);
    floatx2 U0 = {C2[0], C2[1]},   U1 = {C2[4], C2[5]};
    floatx2 U2 = {C2[8], C2[9]},   U3 = {C2[12], C2[13]};
    floatx2 V0 = {C2[2], C2[3]},   V1 = {C2[6], C2[7]};
    floatx2 V2 = {C2[10], C2[11]}, V3 = {C2[14], C2[15]};
    floatx2 nLo01 = pk_fma(U0, D1, pk_mul(U1, D0));
    floatx2 nLo23 = pk_fma(U2, D3, pk_mul(U3, D2));
    floatx2 pLo01 = pk_mul(D0, D1), pLo23 = pk_mul(D2, D3);
    floatx2 nLo   = pk_fma(nLo01, pLo23, pk_mul(nLo23, pLo01));
    floatx2 dLo   = pk_mul(pLo01, pLo23);
    floatx2 nHi01 = pk_fma(V0, G1, pk_mul(V1, G0));
    floatx2 nHi23 = pk_fma(V2, G3, pk_mul(V3, G2));
    floatx2 pHi01 = pk_mul(G0, G1), pHi23 = pk_mul(G2, G3);
    floatx2 nHi   = pk_fma(nHi01, pHi23, pk_mul(nHi23, pHi01));
    floatx2 dHi   = pk_mul(pHi01, pHi23);
    float n8L = __builtin_fmaf(nLo[0], dLo[1], nLo[1] * dLo[0]);
    float d8L = dLo[0] * dLo[1];
    float n8H = __builtin_fmaf(nHi[0], dHi[1], nHi[1] * dHi[0]);
    float d8H = dHi[0] * dHi[1];
    float n16 = __builtin_fmaf(n8L, d8H, n8H * d8L);
    float d16 = d8L * d8H;
    phi = __builtin_fmaf(n16, __builtin_amdgcn_rcpf(d16), phi);
}

// ---------------------------------------------------------------------------
// main: grid = 2 ig x 32 og x 64 btp = 4096 blocks, block = 128 (2 waves);
// wave w -> o = og*2+w, i in [ig*32, ig*32+32). Per i: TWO mfma_32x32x8
// sharing the B-frag: MFMA1 -> a''[h,b], MFMA2 -> u''[h,b].
// C1 runs ONE ITERATION AHEAD (the silu tree needs C1's exponents first);
// C2 is issued at the top of its own iteration — its latency hides under
// the 16-exp2 burst. No LDS, no syncthreads. silu16 = 17 trans + 26 pk +
// 10 scalar per iter. Epilogue: phi * (-1/log2e) + b2sum/NIG, atomic.
// ---------------------------------------------------------------------------
__global__ __launch_bounds__(128, 4) void main_kernel(
        const f16* __restrict__ w1img, const f16* __restrict__ w12img,
        const f16* __restrict__ fimg, const float* __restrict__ b2sum,
        float* __restrict__ out) {
    const int tid  = threadIdx.x;
    const int lane = tid & 63;
    const int wv   = tid >> 6;
    const int btp  = blockIdx.x & 63;
    const int og   = (blockIdx.x >> 6) & 31;
    const int ig   = blockIdx.x >> 11;
    const int o    = __builtin_amdgcn_readfirstlane(og * 2 + wv);
    const size_t ibase = (size_t)ig * IGW;

    const f16* ap1 = w1img  + ibase * 16384 + ((size_t)o   * 64 + lane) * 4;
    const f16* ap2 = w12img + ibase * 16384 + ((size_t)o   * 64 + lane) * 4;
    const f16* bp  = fimg   + ibase * 16384 + ((size_t)btp * 64 + lane) * 4;

    const floatx16 zeroC = {};
    const floatx2  one2  = {1.0f, 1.0f};
    float phi = 0.0f;

    // prologue: frags(0) -> C1(0); frags(1) staged
    f16x4 fa1c = *(const f16x4*)ap1;
    f16x4 fa2c = *(const f16x4*)ap2;
    f16x4 fbc  = *(const f16x4*)bp;
    floatx16 C1c = __builtin_amdgcn_mfma_f32_32x32x8f16(fa1c, fbc, zeroC, 0, 0, 0);
    f16x4 fa1n = *(const f16x4*)(ap1 + 16384);
    f16x4 fa2n = *(const f16x4*)(ap2 + 16384);
    f16x4 fbn  = *(const f16x4*)(bp  + 16384);

#pragma unroll 1
    for (int ii = 0; ii < IGW; ++ii) {
        // current-iter numerators (latency hidden by the exp2 burst below)
        floatx16 C2c = __builtin_amdgcn_mfma_f32_32x32x8f16(fa2c, fbc, zeroC, 0, 0, 0);
        // next-iter exponents, one ahead (garbage at ii=IGW-1 — unused)
        floatx16 C1n = __builtin_amdgcn_mfma_f32_32x32x8f16(fa1n, fbn, zeroC, 0, 0, 0);
        fa2c = fa2n; fbc = fbn;
        // prefetch frags(ii+2); tail overruns into the adjacent ws regions —
        // loaded but never consumed, always inside the workspace (+pad)
        const size_t i2 = (size_t)(ii + 2);
        fa1n = *(const f16x4*)(ap1 + i2 * 16384);
        fa2n = *(const f16x4*)(ap2 + i2 * 16384);
        fbn  = *(const f16x4*)(bp  + i2 * 16384);

        silu16(C1c, C2c, one2, phi);

        C1c = C1n;
    }

    // combine the two row-halves (lane and lane^32 share the same column)
    phi += __shfl_xor(phi, 32, 64);

    if (lane < 32) {
        // accumulated phi = -log2e * sum(a*W2*sigma(a)) -> scale cancels
        float v = phi * (-1.0f / LOG2E) + (1.0f / NIG) * b2sum[o];
        unsafeAtomicAdd(out + (size_t)(btp * 32 + lane) * 64 + o, v);
    }
}

extern "C" void kernel_launch(void* const* d_in, const int* in_sizes, int n_in,
                              void* d_out, int out_size, void* d_ws, size_t ws_size,
                              hipStream_t stream) {
    const float* x  = (const float*)d_in[0];
    const float* W1 = (const float*)d_in[1];
    const float* W2 = (const float*)d_in[2];
    const float* B1 = (const float*)d_in[3];
    const float* B2 = (const float*)d_in[4];
    float* out = (float*)d_out;

    // ws: w1img (2MB) | w12img (2MB) | fimg (2MB) | b2sum (256B) | pad
    // (tail prefetch overruns land in the next region / pad — in-bounds)
    f16*   w1img  = (f16*)d_ws;
    f16*   w12img = w1img  + W1IMG_ELEMS;
    f16*   fimg   = w12img + W1IMG_ELEMS;
    float* b2sum  = (float*)(fimg + FIMG_ELEMS);

    prep_kernel<<<1665, 256, 0, stream>>>(W1, B1, W2, B2, x,
                                          w1img, w12img, fimg, b2sum, out);
    main_kernel<<<NIG * 32 * 64, 128, 0, stream>>>(w1img, w12img, fimg, b2sum, out);
}

// Round 14
// 110.985 us; speedup vs baseline: 1.0529x; 1.0529x over previous
//
#include <hip/hip_runtime.h>
#include <math.h>

typedef _Float16 f16;
typedef f16   f16x4    __attribute__((ext_vector_type(4)));
typedef f16   f16x8    __attribute__((ext_vector_type(8)));
typedef float floatx2  __attribute__((ext_vector_type(2)));
typedef float floatx4  __attribute__((ext_vector_type(4)));
typedef float floatx16 __attribute__((ext_vector_type(16)));

#define LOG2E   1.44269504088896340736f
#define INV_2PI 0.15915494309189533577f

// Problem constants
#define B_SZ  2048
#define DIN   64
#define DOUT  64
#define N_HID 32

#define NIG   4                 // i-groups (8192 blocks)
#define IGW   (DIN / NIG)       // 16 i per block

// Images (built by prep_kernel), K=8-packed for mfma_32x32x8:
//  w1img  f16 [i][o][lane(64)][j(4)]: A1-frag, m=h=lane&31, k=(lane>>5)*4+j.
//         lane<32 -> k=0..3 -> W1[...,{x,s1,s2,s4}]; lane>=32 -> k=4..7 ->
//         {W1[4],W1[5],W1[6],B1}. Scaled by -log2e. MFMA1 -> a'' = -log2e*a.
//  w12img f16: same layout, additionally scaled by W2[i,o,h] per row.
//         MFMA2 -> u'' = -log2e * a * W2 directly.
//  fimg   f16 [i][btp(64)][lane(64)][j(4)]: B-frag; lane<32 {x,s1,s2,s4},
//         lane>=32 {c1,c2,c4,1}.
//  b2sum  f32 [64]: column sums of B2.
#define W1IMG_ELEMS ((size_t)DIN * DOUT * 64 * 4)   // 1,048,576 f16 = 2 MB
#define FIMG_ELEMS  ((size_t)DIN * 64 * 64 * 4)     // 1,048,576 f16 = 2 MB

// ---- packed-f32 (VOP3P) helpers ----
__device__ __forceinline__ floatx2 pk_add(floatx2 a, floatx2 b) {
    floatx2 d; asm("v_pk_add_f32 %0, %1, %2" : "=v"(d) : "v"(a), "v"(b)); return d;
}
__device__ __forceinline__ floatx2 pk_mul(floatx2 a, floatx2 b) {
    floatx2 d; asm("v_pk_mul_f32 %0, %1, %2" : "=v"(d) : "v"(a), "v"(b)); return d;
}
__device__ __forceinline__ floatx2 pk_fma(floatx2 a, floatx2 b, floatx2 c) {
    floatx2 d; asm("v_pk_fma_f32 %0, %1, %2, %3" : "=v"(d) : "v"(a), "v"(b), "v"(c)); return d;
}

// ---------------------------------------------------------------------------
// prep: bid [0,512) w1img, [512,1024) w12img, [1024,1536) fimg,
// [1536,1664) zero out[], 1664 b2sum. sin/cos via HW v_sin/v_cos.
// ---------------------------------------------------------------------------
__global__ __launch_bounds__(256) void prep_kernel(
        const float* __restrict__ W1, const float* __restrict__ B1,
        const float* __restrict__ W2, const float* __restrict__ B2,
        const float* __restrict__ x,
        f16* __restrict__ w1img, f16* __restrict__ w12img,
        f16* __restrict__ fimg, float* __restrict__ b2sum,
        float* __restrict__ out) {
    const int bid = blockIdx.x, tid = threadIdx.x;
    if (bid < 1024) {
        const bool second = bid >= 512;
        int u = (second ? bid - 512 : bid) * 256 + tid;  // [i][o][lane2]
        int lane2 = u & 31, o = (u >> 5) & 63, i = u >> 11;
        int l0 = lane2 * 2;
        f16x8 v;
        if (lane2 < 16) {                    // rows l0,l0+1; k=0..3 -> w[0..3]
#pragma unroll
            for (int t = 0; t < 2; ++t) {
                int m = l0 + t;
                float sc = -LOG2E;
                if (second) sc *= W2[(size_t)(i * 64 + o) * 32 + m];
                const float* w = W1 + (size_t)((i * 64 + o) * 32 + m) * 7;
#pragma unroll
                for (int j = 0; j < 4; ++j) v[t * 4 + j] = (f16)(w[j] * sc);
            }
        } else {                             // rows l0-32..; k=4..7 -> w[4..6],B1
#pragma unroll
            for (int t = 0; t < 2; ++t) {
                int m = l0 - 32 + t;
                float sc = -LOG2E;
                if (second) sc *= W2[(size_t)(i * 64 + o) * 32 + m];
                const float* w = W1 + (size_t)((i * 64 + o) * 32 + m) * 7;
                v[t * 4 + 0] = (f16)(w[4] * sc);
                v[t * 4 + 1] = (f16)(w[5] * sc);
                v[t * 4 + 2] = (f16)(w[6] * sc);
                v[t * 4 + 3] = (f16)(B1[(i * 64 + o) * 32 + m] * sc);
            }
        }
        *(f16x8*)((second ? w12img : w1img) + (size_t)u * 8) = v;
    } else if (bid < 1536) {
        int u = (bid - 1024) * 256 + tid;    // [i][btp][lane2]
        int lane2 = u & 31, btp = (u >> 5) & 63, i = u >> 11;
        int l0 = lane2 * 2;
        f16x8 v;
#pragma unroll
        for (int t = 0; t < 2; ++t) {
            int b = btp * 32 + ((l0 + t) & 31);
            float xv = x[b * 64 + i];
            float s1 = __builtin_amdgcn_sinf(xv * INV_2PI);
            float c1 = __builtin_amdgcn_cosf(xv * INV_2PI);
            float s2 = 2.0f * s1 * c1, c2 = 1.0f - 2.0f * s1 * s1;
            float s4 = 2.0f * s2 * c2, c4 = 1.0f - 2.0f * s2 * s2;
            if (lane2 < 16) { v[t*4+0] = (f16)xv; v[t*4+1] = (f16)s1;
                              v[t*4+2] = (f16)s2; v[t*4+3] = (f16)s4; }
            else            { v[t*4+0] = (f16)c1; v[t*4+1] = (f16)c2;
                              v[t*4+2] = (f16)c4; v[t*4+3] = (f16)1.0f; }
        }
        *(f16x8*)(fimg + (size_t)u * 8) = v;
    } else if (bid < 1664) {
        int t = (bid - 1536) * 256 + tid;    // zero out[] (atomics accumulate)
        floatx4 z = {};
        *(floatx4*)(out + (size_t)t * 4) = z;
    } else if (tid < 64) {
        float s = 0.0f;
        for (int i = 0; i < 64; ++i) s += B2[i * 64 + tid];
        b2sum[tid] = s;
    }
}

// silu-sum over 8 activations given preacts A (a'' = -log2e*a) and
// pre-multiplied U (u'' = W2*a'' from MFMA2): 8-way batched reciprocal,
// sum u_i/(1+2^{a_i}) = n8/d8 with ONE rcp. 13 pk + 4 scalar + 9 trans.
__device__ __forceinline__ void silu8(
        floatx2 A0, floatx2 A1, floatx2 A2, floatx2 A3,
        floatx2 U0, floatx2 U1, floatx2 U2, floatx2 U3,
        floatx2 one2, float& phi) {
    floatx2 E0 = {__builtin_amdgcn_exp2f(A0[0]), __builtin_amdgcn_exp2f(A0[1])};
    floatx2 E1 = {__builtin_amdgcn_exp2f(A1[0]), __builtin_amdgcn_exp2f(A1[1])};
    floatx2 E2 = {__builtin_amdgcn_exp2f(A2[0]), __builtin_amdgcn_exp2f(A2[1])};
    floatx2 E3 = {__builtin_amdgcn_exp2f(A3[0]), __builtin_amdgcn_exp2f(A3[1])};
    floatx2 D0 = pk_add(E0, one2), D1 = pk_add(E1, one2);
    floatx2 D2 = pk_add(E2, one2), D3 = pk_add(E3, one2);
    floatx2 N01 = pk_fma(U0, D1, pk_mul(U1, D0));
    floatx2 N23 = pk_fma(U2, D3, pk_mul(U3, D2));
    floatx2 P01 = pk_mul(D0, D1), P23 = pk_mul(D2, D3);
    floatx2 N   = pk_fma(N01, P23, pk_mul(N23, P01));
    floatx2 DD  = pk_mul(P01, P23);
    float n8 = __builtin_fmaf(N[0], DD[1], N[1] * DD[0]);
    float d8 = DD[0] * DD[1];
    phi = __builtin_fmaf(n8, __builtin_amdgcn_rcpf(d8), phi);
}

// ---------------------------------------------------------------------------
// main (R10 structure, occupancy probe): grid = 4 ig x 32 og x 64 btp =
// 8192 blocks, block = 128 (2 waves); wave w -> o = og*2+w, i in [ig*16,+16).
// Per i: TWO mfma_32x32x8 sharing the B-frag: MFMA1 -> a''[h,b], MFMA2 ->
// u''[h,b]; C consumed immediately (no acc copies — R13's C-rotation cost
// 16 v_movs/iter). __launch_bounds__(128, 8): 16 blocks/CU = 32 waves/CU
// ceiling (VGPR 24 fits 8 waves/SIMD) — tests whether R10's 40% stall is
// hideable dependency latency (occupancy was the only untried lever) or
// trans-pipe saturation. silu8 x2 per iter. Epilogue: phi * (-1/log2e) +
// b2sum/NIG, atomic.
// ---------------------------------------------------------------------------
__global__ __launch_bounds__(128, 8) void main_kernel(
        const f16* __restrict__ w1img, const f16* __restrict__ w12img,
        const f16* __restrict__ fimg, const float* __restrict__ b2sum,
        float* __restrict__ out) {
    const int tid  = threadIdx.x;
    const int lane = tid & 63;
    const int wv   = tid >> 6;
    const int btp  = blockIdx.x & 63;
    const int og   = (blockIdx.x >> 6) & 31;
    const int ig   = blockIdx.x >> 11;
    const int o    = __builtin_amdgcn_readfirstlane(og * 2 + wv);
    const size_t ibase = (size_t)ig * IGW;

    const f16* ap1 = w1img  + ibase * 16384 + ((size_t)o   * 64 + lane) * 4;
    const f16* ap2 = w12img + ibase * 16384 + ((size_t)o   * 64 + lane) * 4;
    const f16* bp  = fimg   + ibase * 16384 + ((size_t)btp * 64 + lane) * 4;

    const floatx16 zeroC = {};
    const floatx2  one2  = {1.0f, 1.0f};
    float phiL = 0.0f, phiH = 0.0f;

    // preload frags(0)
    f16x4 fa1 = *(const f16x4*)ap1;
    f16x4 fa2 = *(const f16x4*)ap2;
    f16x4 fb  = *(const f16x4*)bp;

#pragma unroll 1
    for (int ii = 0; ii < IGW; ++ii) {
        floatx16 C1 = __builtin_amdgcn_mfma_f32_32x32x8f16(fa1, fb, zeroC, 0, 0, 0);
        floatx16 C2 = __builtin_amdgcn_mfma_f32_32x32x8f16(fa2, fb, zeroC, 0, 0, 0);

        // prefetch frags(ii+1); at ii=IGW-1 this overruns 16K f16 into the
        // NEXT ws region (w1img->w12img->fimg->pad) — loaded, never consumed,
        // always inside the workspace
        const size_t i1 = (size_t)(ii + 1);
        fa1 = *(const f16x4*)(ap1 + i1 * 16384);
        fa2 = *(const f16x4*)(ap2 + i1 * 16384);
        fb  = *(const f16x4*)(bp  + i1 * 16384);

        // lo half: r = 0,1 ; hi half: r = 2,3
        silu8((floatx2){C1[0],  C1[1]},  (floatx2){C1[4],  C1[5]},
              (floatx2){C1[8],  C1[9]},  (floatx2){C1[12], C1[13]},
              (floatx2){C2[0],  C2[1]},  (floatx2){C2[4],  C2[5]},
              (floatx2){C2[8],  C2[9]},  (floatx2){C2[12], C2[13]},
              one2, phiL);
        silu8((floatx2){C1[2],  C1[3]},  (floatx2){C1[6],  C1[7]},
              (floatx2){C1[10], C1[11]}, (floatx2){C1[14], C1[15]},
              (floatx2){C2[2],  C2[3]},  (floatx2){C2[6],  C2[7]},
              (floatx2){C2[10], C2[11]}, (floatx2){C2[14], C2[15]},
              one2, phiH);
    }

    float phi = phiL + phiH;
    // combine the two row-halves (lane and lane^32 share the same column)
    phi += __shfl_xor(phi, 32, 64);

    if (lane < 32) {
        // accumulated phi = -log2e * sum(a*W2*sigma(a)) -> scale cancels
        float v = phi * (-1.0f / LOG2E) + (1.0f / NIG) * b2sum[o];
        unsafeAtomicAdd(out + (size_t)(btp * 32 + lane) * 64 + o, v);
    }
}

extern "C" void kernel_launch(void* const* d_in, const int* in_sizes, int n_in,
                              void* d_out, int out_size, void* d_ws, size_t ws_size,
                              hipStream_t stream) {
    const float* x  = (const float*)d_in[0];
    const float* W1 = (const float*)d_in[1];
    const float* W2 = (const float*)d_in[2];
    const float* B1 = (const float*)d_in[3];
    const float* B2 = (const float*)d_in[4];
    float* out = (float*)d_out;

    // ws: w1img (2MB) | w12img (2MB) | fimg (2MB) | b2sum (256B) | pad
    // (tail prefetch overruns land in the next region / pad — in-bounds)
    f16*   w1img  = (f16*)d_ws;
    f16*   w12img = w1img  + W1IMG_ELEMS;
    f16*   fimg   = w12img + W1IMG_ELEMS;
    float* b2sum  = (float*)(fimg + FIMG_ELEMS);

    prep_kernel<<<1665, 256, 0, stream>>>(W1, B1, W2, B2, x,
                                          w1img, w12img, fimg, b2sum, out);
    main_kernel<<<NIG * 32 * 64, 128, 0, stream>>>(w1img, w12img, fimg, b2sum, out);
}